// Round 1
// baseline (710.729 us; speedup 1.0000x reference)
//
#include <hip/hip_runtime.h>
#include <math.h>

#define DF    256
#define GDIM  128
#define ZDIM  128
#define ODIM  16
#define INDIM 274
#define KTOT  256      // hidden*2 (W1 rows 0..127, W2 rows 128..255)
#define TJ    32
#define GCOEFF (-2016.125f)
#define DMAX  2.25f    // beyond this all gaussians underflow to 0

// workspace layout (float offsets)
#define OFF_FD    0        // 4*16
#define OFF_FDSUM 64       // 4
#define OFF_FDSQ  68       // 4
#define OFF_FDOT  72       // 4*256
#define OFF_W144  1096     // 256
#define OFF_SG    1352     // 256
#define OFF_SB    1608     // 256
#define OFF_W3T   1864     // 128*16
#define OFF_CWZ   3912     // 128*256  [z*256+k]
#define OFF_CWG   36680    // 128*256  [g*256+k]
#define OFF_RR    69448    // 4*N*3

__global__ __launch_bounds__(256) void k0_pre(
    const float* __restrict__ nf, const float* __restrict__ Wf,
    const float* __restrict__ gamma, const float* __restrict__ beta,
    const float* __restrict__ W1, const float* __restrict__ W2,
    const float* __restrict__ W3, float* __restrict__ ws) {
  const int t = threadIdx.x;
  float* fd = ws + OFF_FD;
  if (t < 64) {  // fd[bm][c] = normed_fourier[bm,:] . W_fourier[c,:]
    int bm = t >> 4, c = t & 15;
    float s = 0.f;
    for (int f = 0; f < DF; ++f) s += nf[bm * DF + f] * Wf[c * DF + f];
    fd[t] = s;
  }
  {  // per-k folded weights
    int k = t;
    const float* Wk = (k < 128) ? (W1 + (size_t)k * INDIM) : (W2 + (size_t)(k - 128) * INDIM);
    float sgv = 0.f, sbv = 0.f;
    for (int c = 0; c < INDIM; ++c) { float w = Wk[c]; sgv += gamma[c] * w; sbv += beta[c] * w; }
    ws[OFF_SG + k] = sgv;
    ws[OFF_SB + k] = sbv;
    for (int z = 0; z < ZDIM; ++z) ws[OFF_CWZ + z * KTOT + k] = gamma[146 + z] * Wk[146 + z];
    for (int g = 0; g < GDIM; ++g) ws[OFF_CWG + g * KTOT + k] = gamma[16 + g] * Wk[16 + g];
    ws[OFF_W144 + k] = gamma[144] * Wk[144];
    if (k < 128) {
      for (int o = 0; o < ODIM; ++o) ws[OFF_W3T + k * ODIM + o] = W3[o * 128 + k];
    }
  }
  __syncthreads();
  {  // fdot[bm][k] = sum_{c<16} fd[bm][c]*gamma[c]*W[k][c]
    int k = t;
    const float* Wk = (k < 128) ? (W1 + (size_t)k * INDIM) : (W2 + (size_t)(k - 128) * INDIM);
    for (int bm = 0; bm < 4; ++bm) {
      float s = 0.f;
      for (int c = 0; c < 16; ++c) s += fd[bm * 16 + c] * gamma[c] * Wk[c];
      ws[OFF_FDOT + bm * KTOT + k] = s;
    }
  }
  if (t < 4) {
    float s = 0.f, q = 0.f;
    for (int c = 0; c < 16; ++c) { float v = fd[t * 16 + c]; s += v; q += v * v; }
    ws[OFF_FDSUM + t] = s;
    ws[OFF_FDSQ + t] = q;
  }
}

// r_repr[bm][n][c] = sum_a ttra[n][a] * r_noisy[bm][a][c]   (one wave per (bm,n))
__global__ __launch_bounds__(64) void k1_rrepr(
    const float* __restrict__ ttra, const float* __restrict__ rn,
    float* __restrict__ rr, int N, int A) {
  const int b = blockIdx.x;
  const int bm = b / N, n = b % N;
  const int lane = threadIdx.x;
  float a0 = 0.f, a1 = 0.f, a2 = 0.f;
  for (int a = lane; a < A; a += 64) {
    float w = ttra[(size_t)n * A + a];
    const float* rp = rn + ((size_t)bm * A + a) * 3;
    a0 += w * rp[0]; a1 += w * rp[1]; a2 += w * rp[2];
  }
  for (int s = 32; s; s >>= 1) {
    a0 += __shfl_down(a0, s); a1 += __shfl_down(a1, s); a2 += __shfl_down(a2, s);
  }
  if (lane == 0) {
    float* o = rr + ((size_t)bm * N + n) * 3;
    o[0] = a0; o[1] = a1; o[2] = a2;
  }
}

__global__ __launch_bounds__(256) void k2_main(
    const float* __restrict__ rpe, const float* __restrict__ ws,
    float* __restrict__ out, int N) {
  const int t = threadIdx.x;
  const int njt = N / TJ;
  const int i = blockIdx.x / njt;
  const int j0 = (blockIdx.x % njt) * TJ;

  __shared__ float s_rpe[TJ][ZDIM];       // 16 KB
  __shared__ float s_rdot[TJ][KTOT + 1];  // pad 257 -> conflict-free epilogue reads
  __shared__ float s_fdot[4 * KTOT];
  __shared__ float s_w144[KTOT];
  __shared__ float s_sg[KTOT];
  __shared__ float s_sb[KTOT];
  __shared__ float s_w3t[128 * ODIM];
  __shared__ float s_rsum[TJ], s_rsq[TJ];
  __shared__ float s_fdsum[4], s_fdsq[4];
  __shared__ float s_d[4 * TJ];
  __shared__ int   s_glist[4 * TJ];
  __shared__ int   s_gn;
  __shared__ float s_gmat[8][GDIM];
  __shared__ float s_gdot[8][KTOT];
  __shared__ float s_gsum[8], s_gsq[8];

  const float* fdot = ws + OFF_FDOT;
  const float* rr = ws + OFF_RR;

  // stage small tables
  for (int idx = t; idx < 4 * KTOT; idx += 256) s_fdot[idx] = fdot[idx];
  s_w144[t] = ws[OFF_W144 + t];
  s_sg[t] = ws[OFF_SG + t];
  s_sb[t] = ws[OFF_SB + t];
  for (int idx = t; idx < 128 * ODIM; idx += 256) s_w3t[idx] = ws[OFF_W3T + idx];
  if (t < 4) { s_fdsum[t] = ws[OFF_FDSUM + t]; s_fdsq[t] = ws[OFF_FDSQ + t]; }
  if (t == 0) s_gn = 0;

  // stage rpe tile (contiguous 32*128 floats)
  {
    const float4* g4 = (const float4*)(rpe + ((size_t)i * N + j0) * ZDIM);
    float4* l4 = (float4*)&s_rpe[0][0];
    for (int idx = t; idx < TJ * ZDIM / 4; idx += 256) l4[idx] = g4[idx];
  }
  __syncthreads();

  // per-point channel sums of rpe
  if (t < TJ) {
    float s = 0.f, q = 0.f;
    for (int z = 0; z < ZDIM; ++z) { float v = s_rpe[t][z]; s += v; q += v * v; }
    s_rsum[t] = s; s_rsq[t] = q;
  }
  // distances + gauss-needed list
  if (t < 4 * TJ) {
    int bm = t >> 5, p = t & 31;
    const float* ri = rr + ((size_t)bm * N + i) * 3;
    const float* rj = rr + ((size_t)bm * N + j0 + p) * 3;
    float dx = ri[0] - rj[0], dy = ri[1] - rj[1], dz = ri[2] - rj[2];
    float sq = dx * dx + dy * dy + dz * dz;
    float d = sq > 0.f ? sqrtf(sq) : 0.f;
    s_d[t] = d;
    if (d < DMAX) { int slot = atomicAdd(&s_gn, 1); s_glist[slot] = t; }
  }

  // GEMM: rdot[p][k] = sum_z s_rpe[p][z] * CWz[z][k]; thread tile 2p x 16k
  {
    const int kg = t & 15, pg = t >> 4;
    const int k0 = kg * 16, p0 = pg * 2;
    float acc0[16], acc1[16];
#pragma unroll
    for (int q = 0; q < 16; ++q) { acc0[q] = 0.f; acc1[q] = 0.f; }
    const float4* cwz4 = (const float4*)(ws + OFF_CWZ);
#pragma unroll 2
    for (int z = 0; z < ZDIM; ++z) {
      float r0 = s_rpe[p0][z], r1 = s_rpe[p0 + 1][z];
      float w[16];
      const float4* row = cwz4 + z * (KTOT / 4) + (k0 >> 2);
      *(float4*)&w[0] = row[0];
      *(float4*)&w[4] = row[1];
      *(float4*)&w[8] = row[2];
      *(float4*)&w[12] = row[3];
#pragma unroll
      for (int q = 0; q < 16; ++q) { acc0[q] += r0 * w[q]; acc1[q] += r1 * w[q]; }
    }
#pragma unroll
    for (int q = 0; q < 16; ++q) {
      s_rdot[p0][k0 + q] = acc0[q];
      s_rdot[p0 + 1][k0 + q] = acc1[q];
    }
  }
  __syncthreads();

  // epilogue for one instance (bm,p), 2 threads (h=0/1) split k in halves
  auto epilogue = [&](int inst, int h, const float* gdot, float gsum, float gsq) {
    const int bm = inst >> 5, p = inst & 31;
    const float d = s_d[inst];
    const float inv = 1.0f / 274.0f;
    float xsum = s_fdsum[bm] + gsum + d + s_rsum[p];
    float xsq = s_fdsq[bm] + gsq + d * d + s_rsq[p];
    float mu = xsum * inv;
    float var = xsq * inv - mu * mu;
    float rs = rsqrtf(var + 1e-5f);
    float acc[ODIM];
#pragma unroll
    for (int o = 0; o < ODIM; ++o) acc[o] = 0.f;
    const float* fdo = s_fdot + bm * KTOT;
    for (int kk = 0; kk < 64; ++kk) {
      int k = h * 64 + kk;
      float y1 = s_rdot[p][k] + fdo[k] + d * s_w144[k];
      float y2 = s_rdot[p][k + 128] + fdo[k + 128] + d * s_w144[k + 128];
      if (gdot) { y1 += gdot[k]; y2 += gdot[k + 128]; }
      float a1 = rs * (y1 - mu * s_sg[k]) + s_sb[k];
      float a2 = rs * (y2 - mu * s_sg[k + 128]) + s_sb[k + 128];
      float sig = 1.0f / (1.0f + __expf(-a1));
      float hv = a1 * sig * a2;
      const float* w3 = s_w3t + k * ODIM;
#pragma unroll
      for (int o = 0; o < ODIM; ++o) acc[o] += hv * w3[o];
    }
#pragma unroll
    for (int o = 0; o < ODIM; ++o) acc[o] += __shfl_xor(acc[o], 1);
    int j = j0 + p;
#pragma unroll
    for (int oo = 0; oo < 8; ++oo) {
      int o = h * 8 + oo;
      out[(((size_t)bm * ODIM + o) * N + i) * N + j] = acc[o];
    }
  };

  // pass A: all non-gauss instances (2 threads each)
  {
    int inst = t >> 1, h = t & 1;
    if (s_d[inst] >= DMAX) epilogue(inst, h, (const float*)0, 0.f, 0.f);
  }

  // pass B: gauss instances in chunks of 8
  const int gn = s_gn;
  for (int c0 = 0; c0 < gn; c0 += 8) {
    __syncthreads();
    {  // fill gauss rows + per-instance sums
      int il = t >> 5, gi = (t & 31) * 4;
      float ps = 0.f, pq = 0.f;
      if (c0 + il < gn) {
        int inst = s_glist[c0 + il];
        float d = s_d[inst];
#pragma unroll
        for (int u = 0; u < 4; ++u) {
          float off = (float)(2.0 * (gi + u) / 127.0);
          float df = d - off;
          float e = expf(GCOEFF * df * df);
          s_gmat[il][gi + u] = e;
          ps += e; pq += e * e;
        }
      }
      for (int s = 16; s; s >>= 1) { ps += __shfl_xor(ps, s, 32); pq += __shfl_xor(pq, s, 32); }
      if ((t & 31) == 0) { s_gsum[il] = ps; s_gsq[il] = pq; }
    }
    __syncthreads();
    {  // gdot[il][k] = sum_g gmat[il][g] * CWg[g][k]
      int il = t >> 5, k0 = (t & 31) * 8;
      if (c0 + il < gn) {
        float acc[8];
#pragma unroll
        for (int q = 0; q < 8; ++q) acc[q] = 0.f;
        const float* cwg = ws + OFF_CWG;
        for (int g = 0; g < GDIM; ++g) {
          float gv = s_gmat[il][g];
#pragma unroll
          for (int q = 0; q < 8; ++q) acc[q] += gv * cwg[g * KTOT + k0 + q];
        }
#pragma unroll
        for (int q = 0; q < 8; ++q) s_gdot[il][k0 + q] = acc[q];
      }
    }
    __syncthreads();
    if (t < 16) {
      int il = t >> 1, h = t & 1;
      if (c0 + il < gn) {
        int inst = s_glist[c0 + il];
        epilogue(inst, h, &s_gdot[il][0], s_gsum[il], s_gsq[il]);
      }
    }
  }
}

extern "C" void kernel_launch(void* const* d_in, const int* in_sizes, int n_in,
                              void* d_out, int out_size, void* d_ws, size_t ws_size,
                              hipStream_t stream) {
  const float* nf = (const float*)d_in[0];
  const float* rn = (const float*)d_in[1];
  const float* rpe = (const float*)d_in[2];
  const float* ttra = (const float*)d_in[3];
  const float* Wf = (const float*)d_in[4];
  const float* gamma = (const float*)d_in[5];
  const float* beta = (const float*)d_in[6];
  const float* W1 = (const float*)d_in[7];
  const float* W2 = (const float*)d_in[8];
  const float* W3 = (const float*)d_in[9];
  float* out = (float*)d_out;
  float* ws = (float*)d_ws;

  const int BM = in_sizes[0] / DF;          // 4
  const int A = in_sizes[1] / (3 * BM);     // 1536
  const int N = in_sizes[3] / A;            // 384 (B=1)

  k0_pre<<<1, 256, 0, stream>>>(nf, Wf, gamma, beta, W1, W2, W3, ws);
  k1_rrepr<<<BM * N, 64, 0, stream>>>(ttra, rn, ws + OFF_RR, N, A);
  k2_main<<<N * (N / TJ), 256, 0, stream>>>(rpe, ws, out, N);
}

// Round 3
// 271.491 us; speedup vs baseline: 2.6179x; 2.6179x over previous
//
#include <hip/hip_runtime.h>
#include <math.h>

#define ZDIM  128
#define ODIM  16
#define INDIM 274
#define TJ    32
#define GCOEFF (-2016.125f)
#define DMAX  2.25f

// workspace layout (float offsets)
#define OFF_TABP  0        // 128*8  {sg1,sg2,sb1,sb2,w144_1,w144_2,0,0}
#define OFF_FDOP  1024     // 4*128*2
#define OFF_W3T   2048     // 128*16
#define OFF_FDSUM 4096     // 4
#define OFF_FDSQ  4100     // 4
#define OFF_RR    4104     // 4*N*3 = 4608
#define OFF_BHI   8720     // 32768 ushort = 16384 floats (16B aligned)
#define OFF_BLO   25104    // 16384 floats
#define OFF_CWGP  41488    // 128*256 fp32 paired cols
// total 74256 floats

typedef __attribute__((ext_vector_type(8))) short bf16x8;
typedef __attribute__((ext_vector_type(4))) float f32x4;
#define MFMA_BF16 __builtin_amdgcn_mfma_f32_16x16x32_bf16

static __device__ inline ushort f2bf(float x) {
  union { float f; unsigned u; } v; v.f = x;
  unsigned r = v.u + 0x7fffu + ((v.u >> 16) & 1u);
  return (ushort)(r >> 16);
}
static __device__ inline float bf2f(ushort h) {
  union { unsigned u; float f; } v; v.u = ((unsigned)h) << 16;
  return v.f;
}
static __device__ inline void cvt8(float4 a, float4 b, bf16x8& hi, bf16x8& lo) {
  float v[8] = {a.x, a.y, a.z, a.w, b.x, b.y, b.z, b.w};
#pragma unroll
  for (int e = 0; e < 8; ++e) {
    ushort h = f2bf(v[e]);
    hi[e] = (short)h;
    lo[e] = (short)f2bf(v[e] - bf2f(h));
  }
}

__global__ __launch_bounds__(256) void k0a_pre(
    const float* __restrict__ nf, const float* __restrict__ Wf,
    const float* __restrict__ gamma, const float* __restrict__ beta,
    const float* __restrict__ W1, const float* __restrict__ W2,
    const float* __restrict__ W3, float* __restrict__ ws) {
  const int t = threadIdx.x;
  __shared__ float fd[64];
  if (t < 64) {
    int bm = t >> 4, c = t & 15;
    float s = 0.f;
    for (int f = 0; f < 256; ++f) s += nf[bm * 256 + f] * Wf[c * 256 + f];
    fd[t] = s;
  }
  __syncthreads();
  if (t < 128) {
    int q = t;
    const float* r1 = W1 + (size_t)q * INDIM;
    const float* r2 = W2 + (size_t)q * INDIM;
    float sg1 = 0.f, sb1 = 0.f, sg2 = 0.f, sb2 = 0.f;
    for (int c = 0; c < INDIM; ++c) {
      float g = gamma[c], b = beta[c];
      sg1 += g * r1[c]; sb1 += b * r1[c];
      sg2 += g * r2[c]; sb2 += b * r2[c];
    }
    float* tp = ws + OFF_TABP + q * 8;
    tp[0] = sg1; tp[1] = sg2; tp[2] = sb1; tp[3] = sb2;
    tp[4] = gamma[144] * r1[144]; tp[5] = gamma[144] * r2[144];
    tp[6] = 0.f; tp[7] = 0.f;
    for (int o = 0; o < ODIM; ++o) ws[OFF_W3T + q * ODIM + o] = W3[o * 128 + q];
    for (int bm = 0; bm < 4; ++bm) {
      float f1 = 0.f, f2 = 0.f;
      for (int c = 0; c < 16; ++c) {
        float fg = fd[bm * 16 + c] * gamma[c];
        f1 += fg * r1[c]; f2 += fg * r2[c];
      }
      ws[OFF_FDOP + (bm * 128 + q) * 2 + 0] = f1;
      ws[OFF_FDOP + (bm * 128 + q) * 2 + 1] = f2;
    }
  }
  if (t < 4) {
    float s = 0.f, q = 0.f;
    for (int c = 0; c < 16; ++c) { float v = fd[t * 16 + c]; s += v; q += v * v; }
    ws[OFF_FDSUM + t] = s;
    ws[OFF_FDSQ + t] = q;
  }
}

// fill B fragments (bf16 hi/lo, MFMA B-layout, paired column order) + gauss weights
__global__ __launch_bounds__(256) void k0b_frag(
    const float* __restrict__ gamma, const float* __restrict__ W1,
    const float* __restrict__ W2, float* __restrict__ ws) {
  const int flat = blockIdx.x * 256 + threadIdx.x;
  if (flat < 32768) {
    int e = flat & 7, l = (flat >> 3) & 63, ct = (flat >> 9) & 15, kt = flat >> 13;
    int z = kt * 32 + (l >> 4) * 8 + e;
    int n = ct * 16 + (l & 15);
    int q = n >> 1;
    const float* row = (n & 1) ? (W2 + (size_t)q * INDIM) : (W1 + (size_t)q * INDIM);
    float v = gamma[146 + z] * row[146 + z];
    ushort h = f2bf(v);
    ushort lo = f2bf(v - bf2f(h));
    ((ushort*)(ws + OFF_BHI))[flat] = h;
    ((ushort*)(ws + OFF_BLO))[flat] = lo;
  } else {
    int c = flat - 32768;
    int g = c >> 8, n = c & 255, q = n >> 1;
    const float* row = (n & 1) ? (W2 + (size_t)q * INDIM) : (W1 + (size_t)q * INDIM);
    ws[OFF_CWGP + g * 256 + n] = gamma[16 + g] * row[16 + g];
  }
}

// r_repr[bm][n][c] = sum_a ttra[n][a] * r_noisy[bm][a][c]
__global__ __launch_bounds__(64) void k1_rrepr(
    const float* __restrict__ ttra, const float* __restrict__ rn,
    float* __restrict__ rr, int N, int A) {
  const int b = blockIdx.x;
  const int bm = b / N, n = b % N;
  const int lane = threadIdx.x;
  float a0 = 0.f, a1 = 0.f, a2 = 0.f;
  for (int a = lane; a < A; a += 64) {
    float w = ttra[(size_t)n * A + a];
    const float* rp = rn + ((size_t)bm * A + a) * 3;
    a0 += w * rp[0]; a1 += w * rp[1]; a2 += w * rp[2];
  }
  for (int s = 32; s; s >>= 1) {
    a0 += __shfl_down(a0, s); a1 += __shfl_down(a1, s); a2 += __shfl_down(a2, s);
  }
  if (lane == 0) {
    float* o = rr + ((size_t)bm * N + n) * 3;
    o[0] = a0; o[1] = a1; o[2] = a2;
  }
}

__global__ __launch_bounds__(256, 4) void k2_main(
    const float* __restrict__ rpe, const float* __restrict__ ws,
    float* __restrict__ out, int N) {
  const int t = threadIdx.x;
  const int njt = N / TJ;
  const int i = blockIdx.x / njt;
  const int j0 = (blockIdx.x % njt) * TJ;

  __shared__ ushort s_rdotb[32 * 258];   // bf16, paired cols, stride 258
  __shared__ float s_tab[128 * 8];
  __shared__ float s_fdop[4 * 258];
  __shared__ float s_w3t[128 * ODIM];
  __shared__ float s_rsum[32], s_rsq[32];
  __shared__ float s_d[128];
  __shared__ float s_fdsum[4], s_fdsq[4];
  __shared__ int s_glist[128];
  __shared__ int s_gn;
  __shared__ float s_gmat[4][128];
  __shared__ float s_gdot[4][258];
  __shared__ float s_gsum[4], s_gsq[4];

  // --- stage tables (independent LDS regions; read after the barrier) ---
  {
    const float4* src = (const float4*)(ws + OFF_TABP);
    float4* dst = (float4*)s_tab;
    for (int idx = t; idx < 256; idx += 256) dst[idx] = src[idx];
  }
  {
    const float4* src = (const float4*)(ws + OFF_W3T);
    float4* dst = (float4*)s_w3t;
    for (int idx = t; idx < 512; idx += 256) dst[idx] = src[idx];
  }
  for (int idx = t; idx < 1024; idx += 256) {
    int bm = idx >> 8, r = idx & 255;
    s_fdop[bm * 258 + r] = ws[OFF_FDOP + idx];
  }
  if (t < 4) { s_fdsum[t] = ws[OFF_FDSUM + t]; s_fdsq[t] = ws[OFF_FDSQ + t]; }
  if (t == 0) s_gn = 0;

  // REQUIRED: s_gn=0 (wave 0) must be visible before waves 0-1 atomicAdd it.
  // Round-2 regression: removing the rpe-staging barrier let wave 1 increment
  // uninitialized s_gn -> OOB s_glist writes + lost gauss instances.
  __syncthreads();

  // --- distances + gauss list (waves 0-1) ---
  if (t < 128) {
    int bm = t >> 5, p = t & 31;
    const float* rr = ws + OFF_RR;
    const float* ri = rr + ((size_t)bm * N + i) * 3;
    const float* rj = rr + ((size_t)bm * N + j0 + p) * 3;
    float dx = ri[0] - rj[0], dy = ri[1] - rj[1], dz = ri[2] - rj[2];
    float sq = dx * dx + dy * dy + dz * dz;
    float d = sq > 0.f ? sqrtf(sq) : 0.f;
    s_d[t] = d;
    if (d < DMAX) { int slot = atomicAdd(&s_gn, 1); s_glist[slot] = t; }
  }
  // --- rpe row sums (4 threads per row) ---
  if (t < 128) {
    int p = t >> 2, seg = t & 3;
    const float* row = rpe + ((size_t)(i * N) + j0 + p) * ZDIM + seg * 32;
    float s = 0.f, q = 0.f;
    for (int u = 0; u < 32; u += 4) {
      float4 v = *(const float4*)(row + u);
      s += v.x + v.y + v.z + v.w;
      q += v.x * v.x + v.y * v.y + v.z * v.z + v.w * v.w;
    }
    s += __shfl_xor(s, 1); q += __shfl_xor(q, 1);
    s += __shfl_xor(s, 2); q += __shfl_xor(q, 2);
    if (seg == 0) { s_rsum[p] = s; s_rsq[p] = q; }
  }

  // --- MFMA GEMM: rdot[32 rows][256 paired cols] ---
  {
    const int w = t >> 6, l = t & 63, lm = l & 15, lk = l >> 4;
    f32x4 acc[2][4];
#pragma unroll
    for (int mt = 0; mt < 2; ++mt)
#pragma unroll
      for (int nt = 0; nt < 4; ++nt) acc[mt][nt] = (f32x4){0.f, 0.f, 0.f, 0.f};
    const float* a0p = rpe + ((size_t)(i * N) + j0 + lm) * ZDIM;
    const float* a1p = a0p + 16 * ZDIM;
    const ushort* bhip = (const ushort*)(ws + OFF_BHI);
    const ushort* blop = (const ushort*)(ws + OFF_BLO);
#pragma unroll
    for (int kt = 0; kt < 4; ++kt) {
      const int ko = kt * 32 + lk * 8;
      bf16x8 ah0, al0, ah1, al1;
      cvt8(*(const float4*)(a0p + ko), *(const float4*)(a0p + ko + 4), ah0, al0);
      cvt8(*(const float4*)(a1p + ko), *(const float4*)(a1p + ko + 4), ah1, al1);
#pragma unroll
      for (int nt = 0; nt < 4; ++nt) {
        const size_t fo = (((size_t)kt * 16 + w * 4 + nt) * 64 + l) * 8;
        bf16x8 bh = *(const bf16x8*)(bhip + fo);
        bf16x8 bl = *(const bf16x8*)(blop + fo);
        acc[0][nt] = MFMA_BF16(ah0, bh, acc[0][nt], 0, 0, 0);
        acc[0][nt] = MFMA_BF16(al0, bh, acc[0][nt], 0, 0, 0);
        acc[0][nt] = MFMA_BF16(ah0, bl, acc[0][nt], 0, 0, 0);
        acc[1][nt] = MFMA_BF16(ah1, bh, acc[1][nt], 0, 0, 0);
        acc[1][nt] = MFMA_BF16(al1, bh, acc[1][nt], 0, 0, 0);
        acc[1][nt] = MFMA_BF16(ah1, bl, acc[1][nt], 0, 0, 0);
      }
    }
#pragma unroll
    for (int mt = 0; mt < 2; ++mt)
#pragma unroll
      for (int nt = 0; nt < 4; ++nt)
#pragma unroll
        for (int r = 0; r < 4; ++r) {
          int m = mt * 16 + lk * 4 + r;
          int n = w * 64 + nt * 16 + lm;
          s_rdotb[m * 258 + n] = f2bf(acc[mt][nt][r]);
        }
  }
  __syncthreads();

  // --- epilogue: 2 threads per (bm,p) instance, h = k-half ---
  auto epilogue = [&](int inst, int h, const float* gd, float gsum, float gsq) {
    const int bm = inst >> 5, p = inst & 31;
    const float d = s_d[inst];
    const float inv = 1.0f / 274.0f;
    float xsum = s_fdsum[bm] + gsum + d + s_rsum[p];
    float xsq = s_fdsq[bm] + gsq + d * d + s_rsq[p];
    float mu = xsum * inv;
    float var = xsq * inv - mu * mu;
    float rs = rsqrtf(var + 1e-5f);
    float c = rs * mu;
    float acc[ODIM];
#pragma unroll
    for (int o = 0; o < ODIM; ++o) acc[o] = 0.f;
    const ushort* rrow = s_rdotb + p * 258;
    const float* fdo = s_fdop + bm * 258;
    for (int qq = 0; qq < 64; ++qq) {
      int q = h * 64 + qq;
      unsigned u = *(const unsigned*)(rrow + 2 * q);
      float r1 = __uint_as_float(u << 16);
      float r2 = __uint_as_float(u & 0xffff0000u);
      const float* tp = s_tab + q * 8;
      float sg1 = tp[0], sg2 = tp[1], sb1 = tp[2], sb2 = tp[3], w1 = tp[4], w2 = tp[5];
      float f1 = fdo[2 * q], f2 = fdo[2 * q + 1];
      float g1 = 0.f, g2 = 0.f;
      if (gd) { g1 = gd[2 * q]; g2 = gd[2 * q + 1]; }
      float y1 = r1 + f1 + g1 + d * w1;
      float y2 = r2 + f2 + g2 + d * w2;
      float a1 = fmaf(rs, y1, fmaf(-c, sg1, sb1));
      float a2 = fmaf(rs, y2, fmaf(-c, sg2, sb2));
      float sig = 1.0f / (1.0f + __expf(-a1));
      float hv = a1 * sig * a2;
      const float* w3 = s_w3t + q * ODIM;
#pragma unroll
      for (int o = 0; o < ODIM; ++o) acc[o] = fmaf(hv, w3[o], acc[o]);
    }
#pragma unroll
    for (int o = 0; o < ODIM; ++o) acc[o] += __shfl_xor(acc[o], 1);
    int j = j0 + p;
#pragma unroll
    for (int oo = 0; oo < 8; ++oo) {
      int o = h * 8 + oo;
      out[(((size_t)bm * ODIM + o) * N + i) * N + j] = acc[o];
    }
  };

  const int gn = s_gn;

  // pass A: non-gauss instances
  {
    int inst = t >> 1, h = t & 1;
    if (s_d[inst] >= DMAX) epilogue(inst, h, (const float*)0, 0.f, 0.f);
  }

  // pass B: gauss instances, 4 per chunk (one wave each)
  for (int c0 = 0; c0 < gn; c0 += 4) {
    __syncthreads();
    {
      int il = t >> 6, gi = (t & 63) * 2;
      float ps = 0.f, pq = 0.f;
      if (c0 + il < gn) {
        float d = s_d[s_glist[c0 + il]];
#pragma unroll
        for (int u = 0; u < 2; ++u) {
          float off = (float)(2.0 * (gi + u) / 127.0);
          float df = d - off;
          float e = expf(GCOEFF * df * df);
          s_gmat[il][gi + u] = e;
          ps += e; pq += e * e;
        }
      }
      for (int s = 32; s; s >>= 1) { ps += __shfl_xor(ps, s); pq += __shfl_xor(pq, s); }
      if ((t & 63) == 0) { s_gsum[il] = ps; s_gsq[il] = pq; }
    }
    __syncthreads();
    {
      int il = t >> 6, n0 = (t & 63) * 4;
      if (c0 + il < gn) {
        float a0 = 0.f, a1 = 0.f, a2 = 0.f, a3 = 0.f;
        const float* cw = ws + OFF_CWGP;
        for (int g = 0; g < 128; ++g) {
          float gv = s_gmat[il][g];
          float4 wv = *(const float4*)(cw + g * 256 + n0);
          a0 = fmaf(gv, wv.x, a0); a1 = fmaf(gv, wv.y, a1);
          a2 = fmaf(gv, wv.z, a2); a3 = fmaf(gv, wv.w, a3);
        }
        s_gdot[il][n0] = a0; s_gdot[il][n0 + 1] = a1;
        s_gdot[il][n0 + 2] = a2; s_gdot[il][n0 + 3] = a3;
      }
    }
    __syncthreads();
    if (t < 8) {
      int il = t >> 1, h = t & 1;
      if (c0 + il < gn) {
        int inst = s_glist[c0 + il];
        epilogue(inst, h, &s_gdot[il][0], s_gsum[il], s_gsq[il]);
      }
    }
  }
}

extern "C" void kernel_launch(void* const* d_in, const int* in_sizes, int n_in,
                              void* d_out, int out_size, void* d_ws, size_t ws_size,
                              hipStream_t stream) {
  const float* nf = (const float*)d_in[0];
  const float* rn = (const float*)d_in[1];
  const float* rpe = (const float*)d_in[2];
  const float* ttra = (const float*)d_in[3];
  const float* Wf = (const float*)d_in[4];
  const float* gamma = (const float*)d_in[5];
  const float* beta = (const float*)d_in[6];
  const float* W1 = (const float*)d_in[7];
  const float* W2 = (const float*)d_in[8];
  const float* W3 = (const float*)d_in[9];
  float* out = (float*)d_out;
  float* ws = (float*)d_ws;

  const int BM = in_sizes[0] / 256;       // 4
  const int A = in_sizes[1] / (3 * BM);   // 1536
  const int N = in_sizes[3] / A;          // 384

  k0a_pre<<<1, 256, 0, stream>>>(nf, Wf, gamma, beta, W1, W2, W3, ws);
  k0b_frag<<<256, 256, 0, stream>>>(gamma, W1, W2, ws);
  k1_rrepr<<<BM * N, 64, 0, stream>>>(ttra, rn, ws + OFF_RR, N, A);
  k2_main<<<N * (N / TJ), 256, 0, stream>>>(rpe, ws, out, N);
}